// Round 5
// baseline (561.993 us; speedup 1.0000x reference)
//
#include <hip/hip_runtime.h>
#include <hip/hip_bf16.h>

// ---------- types ----------
typedef __attribute__((ext_vector_type(8))) short bf16x8;
typedef __attribute__((ext_vector_type(4))) float f32x4;
typedef __attribute__((ext_vector_type(8))) unsigned short u16x8;
typedef __attribute__((ext_vector_type(4))) unsigned short u16x4;

__device__ __forceinline__ unsigned short f2bf(float x) {
    union { float f; unsigned u; } v; v.f = x;
    unsigned r = v.u + 0x7fff + ((v.u >> 16) & 1);   // RNE
    return (unsigned short)(r >> 16);
}

__device__ __forceinline__ unsigned short f2bf_hw(float x) {
    __hip_bfloat16 h = __float2bfloat16(x);
    return *reinterpret_cast<unsigned short*>(&h);
}

__device__ __forceinline__ void gload16(const void* g, void* l) {
    __builtin_amdgcn_global_load_lds(
        (const __attribute__((address_space(1))) void*)g,
        (__attribute__((address_space(3))) void*)l, 16, 0, 0);
}

// bijective XCD-chunked block swizzle (m204): consecutive swizzled ids stay
// on one XCD so blocks sharing an A-panel share that XCD's L2.
__device__ __forceinline__ int xcd_swz(int bid, int nwg) {
    const int x = bid & 7, pos = bid >> 3;
    const int q = nwg >> 3, r = nwg & 7;
    return (x < r ? x * (q + 1) : r * (q + 1) + (x - r) * q) + pos;
}

// ---------- cast fp32 -> bf16, 8 elems/thread ----------
__global__ __launch_bounds__(256) void cast_bf16_kernel(
    const float* __restrict__ src, unsigned short* __restrict__ dst, int n8) {
    int i = blockIdx.x * 256 + threadIdx.x;
    if (i >= n8) return;
    const float4* s = (const float4*)src + (size_t)i * 2;
    float4 a = s[0], b = s[1];
    u16x8 o;
    o[0] = f2bf(a.x); o[1] = f2bf(a.y); o[2] = f2bf(a.z); o[3] = f2bf(a.w);
    o[4] = f2bf(b.x); o[5] = f2bf(b.y); o[6] = f2bf(b.z); o[7] = f2bf(b.w);
    *(u16x8*)(dst + (size_t)i * 8) = o;
}

// ---------- transpose + cast: src fp32 [R][C] -> dst bf16 [C][R] ----------
__global__ __launch_bounds__(256) void transpose_cast_kernel(
    const float* __restrict__ src, unsigned short* __restrict__ dst, int R, int C) {
    __shared__ float tile[32][33];
    const int bx = blockIdx.x * 32, by = blockIdx.y * 32;
    const int tx = threadIdx.x & 31, ty = threadIdx.x >> 5;  // 32 x 8
#pragma unroll
    for (int i = 0; i < 32; i += 8)
        tile[ty + i][tx] = src[(size_t)(by + ty + i) * C + (bx + tx)];
    __syncthreads();
#pragma unroll
    for (int i = 0; i < 32; i += 8)
        dst[(size_t)(bx + ty + i) * R + (by + tx)] = f2bf(tile[tx][ty + i]);
}

// ---------- GEMM: C[M][N] = A[M][K](bf16) @ BT[N][K](bf16)^T ----------
// m97 structure, 1D grid + XCD-chunked swizzle (T1). nbx = N/128.
template <int OUTBF>
__global__ __launch_bounds__(256) void gemm_kernel(
    const unsigned short* __restrict__ A, const unsigned short* __restrict__ BT,
    void* __restrict__ Cp, int M, int N, int K, int nbx) {
    __shared__ unsigned short Al[2][128 * 32];
    __shared__ unsigned short Bl[2][128 * 32];
    const int t = threadIdx.x;
    const int wid = t >> 6, lane = t & 63;
    const int l15 = lane & 15, lg = lane >> 4;
    const int wg = xcd_swz(blockIdx.x, gridDim.x);
    const int bm = (wg / nbx) * 128, bn = (wg % nbx) * 128;
    const int wm = (wid >> 1) * 64, wn = (wid & 1) * 64;

    f32x4 acc[4][4];
#pragma unroll
    for (int i = 0; i < 4; ++i)
#pragma unroll
        for (int j = 0; j < 4; ++j) acc[i][j] = (f32x4)(0.f);

    const int nk = K >> 5;
    const int c0 = t, c1 = t + 256;

    auto stage = [&](int buf, int kt) {
        const unsigned short* Ab = A + (size_t)bm * K + kt * 32;
        const unsigned short* Bb = BT + (size_t)bn * K + kt * 32;
        gload16(Ab + (size_t)(c0 >> 2) * K + (c0 & 3) * 8, &Al[buf][wid * 64 * 8]);
        gload16(Ab + (size_t)(c1 >> 2) * K + (c1 & 3) * 8, &Al[buf][(256 + wid * 64) * 8]);
        gload16(Bb + (size_t)(c0 >> 2) * K + (c0 & 3) * 8, &Bl[buf][wid * 64 * 8]);
        gload16(Bb + (size_t)(c1 >> 2) * K + (c1 & 3) * 8, &Bl[buf][(256 + wid * 64) * 8]);
    };

    stage(0, 0);
    __syncthreads();
    for (int kt = 0; kt < nk; ++kt) {
        const int cur = kt & 1;
        if (kt + 1 < nk) stage(cur ^ 1, kt + 1);
        bf16x8 af[4], bfr[4];
#pragma unroll
        for (int i = 0; i < 4; ++i) {
            af[i]  = *(const bf16x8*)&Al[cur][(wm + i * 16 + l15) * 32 + lg * 8];
            bfr[i] = *(const bf16x8*)&Bl[cur][(wn + i * 16 + l15) * 32 + lg * 8];
        }
#pragma unroll
        for (int i = 0; i < 4; ++i)
#pragma unroll
            for (int j = 0; j < 4; ++j)
                acc[i][j] = __builtin_amdgcn_mfma_f32_16x16x32_bf16(af[i], bfr[j], acc[i][j], 0, 0, 0);
        __syncthreads();
    }

#pragma unroll
    for (int i = 0; i < 4; ++i)
#pragma unroll
        for (int j = 0; j < 4; ++j)
#pragma unroll
            for (int r = 0; r < 4; ++r) {
                const int row = bm + wm + i * 16 + lg * 4 + r;
                const int col = bn + wn + j * 16 + l15;
                if (OUTBF) ((unsigned short*)Cp)[(size_t)row * N + col] = f2bf(acc[i][j][r]);
                else       ((float*)Cp)[(size_t)row * N + col] = acc[i][j][r];
            }
}

// ---------- flash attention v4 (MQA, ALiBi, causal, swapped-QK softmax) ----------
// Balanced causal pairing: block p handles q-blocks {p, 31-p} (33 KV64-tiles).
// 4 waves; wave w owns q rows qblk*64 + w*16 .. +15. KVBLK=64.
// QK^T computed SWAPPED: mfma(K, Q) -> D[row=kv][col=q]; each lane owns one
//   q-row (q = q0w + l15) x 16 kv entries -> in-lane softmax, 4 shfl_xor total.
// K : LDS [64][128], byte^=(row&7)<<4, staged via gload16 w/ pre-swizzled src.
// V^T: LDS [128][64] 128B rows, byte^=(dd&7)<<4, manual reg transpose.
// P : per-wave LDS [16 q][64 kv] 128B rows, byte^=(q&7)<<4, 4x ds_write_b64.
__global__ __launch_bounds__(256, 4) void attn_kernel(
    const unsigned short* __restrict__ qkv, unsigned short* __restrict__ attn, int S) {
    constexpr int LD = 4352;
    __shared__ unsigned short Kl[64 * 128];
    __shared__ unsigned short Vt[128 * 64];
    __shared__ unsigned short Pl[4][16 * 64];
    const int t = threadIdx.x, wid = t >> 6;
    const int lane = t & 63, l15 = lane & 15, lg = lane >> 4;
    const int h = blockIdx.y, b = blockIdx.z;
    const size_t rb = (size_t)b * S;
    const int nQB = S >> 6;                       // 32
    const float scale2 = 0.08838834764831845f * 1.4426950408889634f;
    const float slope2 = exp2f(-0.25f * (float)(h + 1)) * 1.4426950408889634f;
    const float sr1 = slope2, sr2 = slope2 * 2.f, sr3 = slope2 * 3.f;

    for (int half = 0; half < 2; ++half) {
        const int qblk = half ? (nQB - 1 - (int)blockIdx.x) : (int)blockIdx.x;
        const int q0w = qblk * 64 + wid * 16;
        const int qlane = q0w + l15;              // this lane's q-row for softmax
        const float aq = slope2 * (float)qlane;

        bf16x8 qf[4];
        {
            const unsigned short* qrow = qkv + (rb + qlane) * LD + h * 128 + lg * 8;
#pragma unroll
            for (int j = 0; j < 4; ++j) qf[j] = *(const bf16x8*)(qrow + j * 32);
        }
        f32x4 o[8];
#pragma unroll
        for (int i = 0; i < 8; ++i) o[i] = (f32x4)(0.f);
        float m_ = -1e30f, l_ = 0.f;

        const int ntile = qblk + 1;
        for (int tile = 0; tile < ntile; ++tile) {
            const int t0 = tile * 64;
            // ---- stage K (gload16, pre-swizzled source) ----
            {
                const char* kbase = (const char*)(qkv + (rb + t0) * LD + 4096);
#pragma unroll
                for (int i = 0; i < 4; ++i) {
                    const int c = i * 256 + t;
                    const int krow = c >> 4;
                    gload16(kbase + (size_t)krow * (LD * 2) + (((c & 15) * 16) ^ ((krow & 7) << 4)),
                            (char*)Kl + (i * 256 + wid * 64) * 16);
                }
            }
            // ---- stage V^T: lane = kv row, wave = 32-wide d block ----
            {
                const unsigned short* vs = qkv + (rb + t0 + lane) * LD + 4224 + wid * 32;
                u16x8 v0 = *(const u16x8*)vs;
                u16x8 v1 = *(const u16x8*)(vs + 8);
                u16x8 v2 = *(const u16x8*)(vs + 16);
                u16x8 v3 = *(const u16x8*)(vs + 24);
                const int kb = 2 * lane;
#pragma unroll
                for (int e = 0; e < 8; ++e) {
                    int dd = wid * 32 + e;
                    *(unsigned short*)((char*)Vt + dd * 128 + (kb ^ ((dd & 7) << 4))) = v0[e];
                    dd += 8;
                    *(unsigned short*)((char*)Vt + dd * 128 + (kb ^ ((dd & 7) << 4))) = v1[e];
                    dd += 8;
                    *(unsigned short*)((char*)Vt + dd * 128 + (kb ^ ((dd & 7) << 4))) = v2[e];
                    dd += 8;
                    *(unsigned short*)((char*)Vt + dd * 128 + (kb ^ ((dd & 7) << 4))) = v3[e];
                }
            }
            __syncthreads();

            // ---- QK^T SWAPPED: D[row=kv (lg*4+r within ct-block)][col=q (l15)] ----
            f32x4 s4[4];
#pragma unroll
            for (int ct = 0; ct < 4; ++ct) {
                s4[ct] = (f32x4)(0.f);
                const int row = ct * 16 + l15;
                const int swz = (row & 7) << 4;
#pragma unroll
                for (int j = 0; j < 4; ++j) {
                    bf16x8 kf = *(const bf16x8*)((const char*)Kl + row * 256 +
                                                 ((j * 64 + lg * 16) ^ swz));
                    s4[ct] = __builtin_amdgcn_mfma_f32_16x16x32_bf16(kf, qf[j], s4[ct], 0, 0, 0);
                }
            }

            // ---- in-lane online softmax (log2 domain); lane owns q = qlane ----
            const float base = slope2 * (float)(t0 + lg * 4) - aq;
            float p4[4][4];
            float mx = -1e30f;
            const bool lastt = (tile == ntile - 1);
            const int dbase = t0 + lg * 4 - qlane;
#pragma unroll
            for (int ct = 0; ct < 4; ++ct) {
                const float bbc = base + slope2 * 16.f * (float)ct;
#pragma unroll
                for (int r = 0; r < 4; ++r) {
                    float sc = fmaf(s4[ct][r], scale2,
                                    bbc + (r == 0 ? 0.f : (r == 1 ? sr1 : (r == 2 ? sr2 : sr3))));
                    if (lastt && (dbase + ct * 16 + r > 0)) sc = -1e30f;
                    p4[ct][r] = sc;
                    mx = fmaxf(mx, sc);
                }
            }
            mx = fmaxf(mx, __shfl_xor(mx, 16));
            mx = fmaxf(mx, __shfl_xor(mx, 32));

            // defer-max (T13): rescale only if some row grew > 8 (log2)
            if (!__all(mx <= m_ + 8.0f)) {
                const float mnew = fmaxf(m_, mx);
                const float corr = exp2f(m_ - mnew);
                m_ = mnew;
                l_ *= corr;
                float cr[4];
#pragma unroll
                for (int r = 0; r < 4; ++r) cr[r] = __shfl(corr, lg * 4 + r);
#pragma unroll
                for (int n = 0; n < 8; ++n) {
                    o[n][0] *= cr[0]; o[n][1] *= cr[1];
                    o[n][2] *= cr[2]; o[n][3] *= cr[3];
                }
            }

            float rs = 0.f;
#pragma unroll
            for (int ct = 0; ct < 4; ++ct)
#pragma unroll
                for (int r = 0; r < 4; ++r) {
                    const float pv = exp2f(p4[ct][r] - m_);
                    p4[ct][r] = pv;
                    rs += pv;
                }
            rs += __shfl_xor(rs, 16);
            rs += __shfl_xor(rs, 32);
            l_ += rs;

            // ---- P store: lane writes row q=l15, kv cols ct*16+lg*4 .. +3 ----
            {
                char* pb = (char*)&Pl[wid][0] + l15 * 128;
                const int swz = (l15 & 7) << 4;
#pragma unroll
                for (int ct = 0; ct < 4; ++ct) {
                    u16x4 w;
                    w[0] = f2bf_hw(p4[ct][0]); w[1] = f2bf_hw(p4[ct][1]);
                    w[2] = f2bf_hw(p4[ct][2]); w[3] = f2bf_hw(p4[ct][3]);
                    *(u16x4*)(pb + ((ct * 32 + lg * 8) ^ swz)) = w;
                }
            }

            // ---- PV: O += P @ V  (corr already applied to o) ----
            const char* pb = (const char*)&Pl[wid][0] + l15 * 128;
            const int pswz = (l15 & 7) << 4;
            bf16x8 pa0 = *(const bf16x8*)(pb + ((lg * 16) ^ pswz));
            bf16x8 pa1 = *(const bf16x8*)(pb + ((64 + lg * 16) ^ pswz));
#pragma unroll
            for (int n = 0; n < 8; ++n) {
                const int dd = n * 16 + l15;
                const int vswz = (dd & 7) << 4;
                bf16x8 vf0 = *(const bf16x8*)((const char*)Vt + dd * 128 + ((lg * 16) ^ vswz));
                bf16x8 vf1 = *(const bf16x8*)((const char*)Vt + dd * 128 + ((64 + lg * 16) ^ vswz));
                f32x4 a4 = __builtin_amdgcn_mfma_f32_16x16x32_bf16(pa0, vf0, o[n], 0, 0, 0);
                o[n] = __builtin_amdgcn_mfma_f32_16x16x32_bf16(pa1, vf1, a4, 0, 0, 0);
            }
            __syncthreads();
        }

        // ---- epilogue: rinv lives on lane l15=q; broadcast to o-rows ----
        const float rl = 1.f / l_;
        float rv[4];
#pragma unroll
        for (int r = 0; r < 4; ++r) rv[r] = __shfl(rl, lg * 4 + r);
#pragma unroll
        for (int n = 0; n < 8; ++n)
#pragma unroll
            for (int r = 0; r < 4; ++r) {
                const int q = q0w + lg * 4 + r;
                attn[(rb + q) * 4096 + h * 128 + n * 16 + l15] = f2bf(o[n][r] * rv[r]);
            }
    }
}

// ---------- launch ----------
extern "C" void kernel_launch(void* const* d_in, const int* in_sizes, int n_in,
                              void* d_out, int out_size, void* d_ws, size_t ws_size,
                              hipStream_t stream) {
    const float* hidden = (const float*)d_in[0];
    const float* Wqkv   = (const float*)d_in[1];
    const float* Wo     = (const float*)d_in[2];
    float* out = (float*)d_out;
    char* ws = (char*)d_ws;

    const int B = 2, S = 2048, H = 4096, NQ = 4352;
    const int M = B * S;

    unsigned short* hb  = (unsigned short*)(ws);                            // hidden bf16, later attn out
    unsigned short* wT  = (unsigned short*)(ws + 33554432);                 // WqkvT, later WoT
    unsigned short* qkv = (unsigned short*)(ws + 33554432 + 35651584);      // qkv bf16

    cast_bf16_kernel<<<(M * H / 8) / 256, 256, 0, stream>>>(hidden, hb, M * H / 8);
    transpose_cast_kernel<<<dim3(NQ / 32, H / 32), 256, 0, stream>>>(Wqkv, wT, H, NQ);
    gemm_kernel<1><<<dim3((NQ / 128) * (M / 128)), 256, 0, stream>>>(hb, wT, qkv, M, NQ, H, NQ / 128);
    transpose_cast_kernel<<<dim3(H / 32, H / 32), 256, 0, stream>>>(Wo, wT, H, H);
    attn_kernel<<<dim3(16, 32, 2), 256, 0, stream>>>(qkv, hb, S);
    gemm_kernel<0><<<dim3((H / 128) * (M / 128)), 256, 0, stream>>>(hb, wT, out, M, H, H, H / 128);
}

// Round 7
// 554.852 us; speedup vs baseline: 1.0129x; 1.0129x over previous
//
#include <hip/hip_runtime.h>
#include <hip/hip_bf16.h>

// ---------- types ----------
typedef __attribute__((ext_vector_type(8))) short bf16x8;
typedef __attribute__((ext_vector_type(4))) float f32x4;
typedef __attribute__((ext_vector_type(8))) unsigned short u16x8;
typedef __attribute__((ext_vector_type(4))) unsigned short u16x4;

__device__ __forceinline__ unsigned short f2bf(float x) {
    union { float f; unsigned u; } v; v.f = x;
    unsigned r = v.u + 0x7fff + ((v.u >> 16) & 1);   // RNE
    return (unsigned short)(r >> 16);
}

__device__ __forceinline__ unsigned short f2bf_hw(float x) {
    __hip_bfloat16 h = __float2bfloat16(x);
    return *reinterpret_cast<unsigned short*>(&h);
}

__device__ __forceinline__ void gload16(const void* g, void* l) {
    __builtin_amdgcn_global_load_lds(
        (const __attribute__((address_space(1))) void*)g,
        (__attribute__((address_space(3))) void*)l, 16, 0, 0);
}

// ---------- cast fp32 -> bf16, 8 elems/thread ----------
__global__ __launch_bounds__(256) void cast_bf16_kernel(
    const float* __restrict__ src, unsigned short* __restrict__ dst, int n8) {
    int i = blockIdx.x * 256 + threadIdx.x;
    if (i >= n8) return;
    const float4* s = (const float4*)src + (size_t)i * 2;
    float4 a = s[0], b = s[1];
    u16x8 o;
    o[0] = f2bf(a.x); o[1] = f2bf(a.y); o[2] = f2bf(a.z); o[3] = f2bf(a.w);
    o[4] = f2bf(b.x); o[5] = f2bf(b.y); o[6] = f2bf(b.z); o[7] = f2bf(b.w);
    *(u16x8*)(dst + (size_t)i * 8) = o;
}

// ---------- transpose + cast: src fp32 [R][C] -> dst bf16 [C][R] ----------
__global__ __launch_bounds__(256) void transpose_cast_kernel(
    const float* __restrict__ src, unsigned short* __restrict__ dst, int R, int C) {
    __shared__ float tile[32][33];
    const int bx = blockIdx.x * 32, by = blockIdx.y * 32;
    const int tx = threadIdx.x & 31, ty = threadIdx.x >> 5;  // 32 x 8
#pragma unroll
    for (int i = 0; i < 32; i += 8)
        tile[ty + i][tx] = src[(size_t)(by + ty + i) * C + (bx + tx)];
    __syncthreads();
#pragma unroll
    for (int i = 0; i < 32; i += 8)
        dst[(size_t)(bx + ty + i) * R + (by + tx)] = f2bf(tile[tx][ty + i]);
}

// ---------- GEMM (m97 128x128 structure), used for GEMM1 (N=4352) ----------
template <int OUTBF>
__global__ __launch_bounds__(256) void gemm_kernel(
    const unsigned short* __restrict__ A, const unsigned short* __restrict__ BT,
    void* __restrict__ Cp, int M, int N, int K) {
    __shared__ unsigned short Al[2][128 * 32];
    __shared__ unsigned short Bl[2][128 * 32];
    const int t = threadIdx.x;
    const int wid = t >> 6, lane = t & 63;
    const int l15 = lane & 15, lg = lane >> 4;
    const int bm = blockIdx.y * 128, bn = blockIdx.x * 128;
    const int wm = (wid >> 1) * 64, wn = (wid & 1) * 64;

    f32x4 acc[4][4];
#pragma unroll
    for (int i = 0; i < 4; ++i)
#pragma unroll
        for (int j = 0; j < 4; ++j) acc[i][j] = (f32x4)(0.f);

    const int nk = K >> 5;
    const int c0 = t, c1 = t + 256;

    auto stage = [&](int buf, int kt) {
        const unsigned short* Ab = A + (size_t)bm * K + kt * 32;
        const unsigned short* Bb = BT + (size_t)bn * K + kt * 32;
        gload16(Ab + (size_t)(c0 >> 2) * K + (c0 & 3) * 8, &Al[buf][wid * 64 * 8]);
        gload16(Ab + (size_t)(c1 >> 2) * K + (c1 & 3) * 8, &Al[buf][(256 + wid * 64) * 8]);
        gload16(Bb + (size_t)(c0 >> 2) * K + (c0 & 3) * 8, &Bl[buf][wid * 64 * 8]);
        gload16(Bb + (size_t)(c1 >> 2) * K + (c1 & 3) * 8, &Bl[buf][(256 + wid * 64) * 8]);
    };

    stage(0, 0);
    __syncthreads();
    for (int kt = 0; kt < nk; ++kt) {
        const int cur = kt & 1;
        if (kt + 1 < nk) stage(cur ^ 1, kt + 1);
        bf16x8 af[4], bfr[4];
#pragma unroll
        for (int i = 0; i < 4; ++i) {
            af[i]  = *(const bf16x8*)&Al[cur][(wm + i * 16 + l15) * 32 + lg * 8];
            bfr[i] = *(const bf16x8*)&Bl[cur][(wn + i * 16 + l15) * 32 + lg * 8];
        }
#pragma unroll
        for (int i = 0; i < 4; ++i)
#pragma unroll
            for (int j = 0; j < 4; ++j)
                acc[i][j] = __builtin_amdgcn_mfma_f32_16x16x32_bf16(af[i], bfr[j], acc[i][j], 0, 0, 0);
        __syncthreads();
    }

#pragma unroll
    for (int i = 0; i < 4; ++i)
#pragma unroll
        for (int j = 0; j < 4; ++j)
#pragma unroll
            for (int r = 0; r < 4; ++r) {
                const int row = bm + wm + i * 16 + lg * 4 + r;
                const int col = bn + wn + j * 16 + l15;
                if (OUTBF) ((unsigned short*)Cp)[(size_t)row * N + col] = f2bf(acc[i][j][r]);
                else       ((float*)Cp)[(size_t)row * N + col] = acc[i][j][r];
            }
}

// ---------- GEMM2: 256x256 8-phase (T2+T3+T4+T5), race-free schedule ----------
// 8 waves (2 A-halves x 4 N-quarters), BK=64, LDS 128KB = 2buf x {A0,A1,B0,B1}
// 16KB halves, planar [plane(32c)][128r][32c], st_16x32 swizzle bit9->bit5.
// Reads: A-all+B(n0) at ph1/ph5, B(n1) at ph3/ph7. Quadrants: m0n0,m1n0,m1n1,m0n1.
// Stages (1 half/phase): ph1 Bb(1,1)<-kto | ph2..5 buf0<-kt+2 {A0,A1,B0,B1}
//                        | ph6..8 Ab(1,0),Ab(1,1),Bb(1,0)<-kt+3.
// Every stage issues after the barrier ending its target's last read phase.
// vmcnt(6) at ph4/ph8 completes exactly the 4 halves read next (3 in flight).
#define SYNC1() do { __builtin_amdgcn_s_barrier(); \
    asm volatile("s_waitcnt lgkmcnt(0)" ::: "memory"); } while (0)
#define GATE6() do { asm volatile("s_waitcnt vmcnt(6)" ::: "memory"); \
    __builtin_amdgcn_s_barrier(); __builtin_amdgcn_sched_barrier(0); } while (0)

template <int OUTBF>
__global__ __launch_bounds__(512, 2) void gemm256_kernel(
    const unsigned short* __restrict__ A, const unsigned short* __restrict__ BT,
    void* __restrict__ Cp, int K, int N) {
    __shared__ __align__(16) char lds[131072];
    const int t = threadIdx.x;
    const int wid = t >> 6, lane = t & 63;
    const int l15 = lane & 15, lg = lane >> 4;
    // rect XCD map: 16x16 tile grid, each XCD owns a 4x8 rectangle
    const int xcd = blockIdx.x & 7, idx = blockIdx.x >> 3;
    const int bm = ((xcd >> 1) * 4 + (idx >> 3)) * 256;
    const int bn = ((xcd & 1) * 8 + (idx & 7)) * 256;
    const int wmh = wid >> 2;            // wave A-half (rows wmh*128)
    const int wq  = wid & 3;             // wave N quarter (cols wq*64)
    const int bhf = wq >> 1;             // B half this wave reads
    const int br0 = (wq & 1) * 64;       // row base within B half

    auto Ab = [&](int b, int h) -> char* { return lds + ((b * 2 + h) << 14); };
    auto Bb = [&](int b, int h) -> char* { return lds + 65536 + ((b * 2 + h) << 14); };

    // stage one 16KB half: linear LDS dest, inverse-swizzled global source
    auto stage = [&](char* halfBase, const unsigned short* mat, int rowBase, int kt) {
#pragma unroll
        for (int j = 0; j < 2; ++j) {
            const int dbase = ((j << 3) + wid) << 10;
            const int q = (dbase + lane * 16) ^ (lane & 32);   // logical byte
            const int p = q >> 13, r = (q >> 6) & 127, cb = q & 63;
            gload16(mat + (size_t)(rowBase + r) * K + (kt << 6) + (p << 5) + (cb >> 1),
                    halfBase + dbase);
        }
    };

    f32x4 acc[8][4];
#pragma unroll
    for (int i = 0; i < 8; ++i)
#pragma unroll
        for (int j = 0; j < 4; ++j) acc[i][j] = (f32x4)(0.f);

    bf16x8 af[8][2];   // all 128 rows of wave's A-half, K=64
    bf16x8 bfr[2][2];  // one 32-row B quadrant, K=64

    auto ldA = [&](int b) {
        const char* base = Ab(b, wmh);
#pragma unroll
        for (int i = 0; i < 8; ++i) {
            const int r = i * 16 + l15;
            const int sw = ((r >> 3) & 1) << 5;
#pragma unroll
            for (int kk = 0; kk < 2; ++kk)
                af[i][kk] = *(const bf16x8*)(base + ((kk * 8192 + r * 64 + lg * 16) ^ sw));
        }
    };
    auto ldB = [&](int b, int nh) {
        const char* base = Bb(b, bhf);
#pragma unroll
        for (int i = 0; i < 2; ++i) {
            const int r = br0 + (nh * 2 + i) * 16 + l15;
            const int sw = ((r >> 3) & 1) << 5;
#pragma unroll
            for (int kk = 0; kk < 2; ++kk)
                bfr[i][kk] = *(const bf16x8*)(base + ((kk * 8192 + r * 64 + lg * 16) ^ sw));
        }
    };
    auto MF = [&](int mh, int nh) {
        __builtin_amdgcn_s_setprio(1);
#pragma unroll
        for (int i = 0; i < 4; ++i)
#pragma unroll
            for (int j = 0; j < 2; ++j)
#pragma unroll
                for (int kk = 0; kk < 2; ++kk)
                    acc[mh * 4 + i][nh * 2 + j] = __builtin_amdgcn_mfma_f32_16x16x32_bf16(
                        af[mh * 4 + i][kk], bfr[j][kk], acc[mh * 4 + i][nh * 2 + j], 0, 0, 0);
        __builtin_amdgcn_s_setprio(0);
    };

    // ---- prologue: buf0 fully <- kt0; buf1 {A0,A1,B0} <- kt1 ----
    stage(Ab(0, 0), A, bm, 0);
    stage(Ab(0, 1), A, bm + 128, 0);
    stage(Bb(0, 0), BT, bn, 0);
    stage(Bb(0, 1), BT, bn + 128, 0);
    stage(Ab(1, 0), A, bm, 1);
    stage(Ab(1, 1), A, bm + 128, 1);
    stage(Bb(1, 0), BT, bn, 1);
    asm volatile("s_waitcnt vmcnt(6)" ::: "memory");   // buf0 landed
    __builtin_amdgcn_s_barrier();
    __builtin_amdgcn_sched_barrier(0);

    const int kmask = (K >> 6) - 1;
    const int niter = K >> 7;
    for (int it = 0; it < niter; ++it) {
        const int kto = 2 * it + 1;
        const int kne = (2 * it + 2) & kmask;   // wraps harmlessly on last iter
        const int kno = (2 * it + 3) & kmask;
        // ph1: read buf0 A-all + B(n0); stage buf1.B1 <- kto
        ldA(0); ldB(0, 0);
        stage(Bb(1, 1), BT, bn + 128, kto);
        SYNC1(); MF(0, 0); __builtin_amdgcn_s_barrier();
        // ph2: stage buf0.A0 <- kne (buf0.A last read ph1)
        stage(Ab(0, 0), A, bm, kne);
        SYNC1(); MF(1, 0); __builtin_amdgcn_s_barrier();
        // ph3: read buf0 B(n1); stage buf0.A1 <- kne
        ldB(0, 1);
        stage(Ab(0, 1), A, bm + 128, kne);
        SYNC1(); MF(1, 1); __builtin_amdgcn_s_barrier();
        // ph4: stage buf0.B0 <- kne (buf0.B last read ph3); gate buf1
        stage(Bb(0, 0), BT, bn, kne);
        SYNC1(); MF(0, 1); GATE6();
        // ph5: read buf1 A-all + B(n0); stage buf0.B1 <- kne
        ldA(1); ldB(1, 0);
        stage(Bb(0, 1), BT, bn + 128, kne);
        SYNC1(); MF(0, 0); __builtin_amdgcn_s_barrier();
        // ph6: stage buf1.A0 <- kno (buf1.A last read ph5)
        stage(Ab(1, 0), A, bm, kno);
        SYNC1(); MF(1, 0); __builtin_amdgcn_s_barrier();
        // ph7: read buf1 B(n1); stage buf1.A1 <- kno
        ldB(1, 1);
        stage(Ab(1, 1), A, bm + 128, kno);
        SYNC1(); MF(1, 1); __builtin_amdgcn_s_barrier();
        // ph8: stage buf1.B0 <- kno (buf1.B last read ph7); gate buf0
        stage(Bb(1, 0), BT, bn, kno);
        SYNC1(); MF(0, 1); GATE6();
    }

#pragma unroll
    for (int mi = 0; mi < 8; ++mi)
#pragma unroll
        for (int ni = 0; ni < 4; ++ni)
#pragma unroll
            for (int rr = 0; rr < 4; ++rr) {
                const size_t off = (size_t)(bm + wmh * 128 + mi * 16 + lg * 4 + rr) * N +
                                   bn + wq * 64 + ni * 16 + l15;
                if (OUTBF) ((unsigned short*)Cp)[off] = f2bf(acc[mi][ni][rr]);
                else       ((float*)Cp)[off] = acc[mi][ni][rr];
            }
}

// ---------- flash attention v4 (MQA, ALiBi, causal, swapped-QK softmax) ----------
__global__ __launch_bounds__(256, 4) void attn_kernel(
    const unsigned short* __restrict__ qkv, unsigned short* __restrict__ attn, int S) {
    constexpr int LD = 4352;
    __shared__ unsigned short Kl[64 * 128];
    __shared__ unsigned short Vt[128 * 64];
    __shared__ unsigned short Pl[4][16 * 64];
    const int t = threadIdx.x, wid = t >> 6;
    const int lane = t & 63, l15 = lane & 15, lg = lane >> 4;
    const int h = blockIdx.y, b = blockIdx.z;
    const size_t rb = (size_t)b * S;
    const int nQB = S >> 6;                       // 32
    const float scale2 = 0.08838834764831845f * 1.4426950408889634f;
    const float slope2 = exp2f(-0.25f * (float)(h + 1)) * 1.4426950408889634f;
    const float sr1 = slope2, sr2 = slope2 * 2.f, sr3 = slope2 * 3.f;

    for (int half = 0; half < 2; ++half) {
        const int qblk = half ? (nQB - 1 - (int)blockIdx.x) : (int)blockIdx.x;
        const int q0w = qblk * 64 + wid * 16;
        const int qlane = q0w + l15;
        const float aq = slope2 * (float)qlane;

        bf16x8 qf[4];
        {
            const unsigned short* qrow = qkv + (rb + qlane) * LD + h * 128 + lg * 8;
#pragma unroll
            for (int j = 0; j < 4; ++j) qf[j] = *(const bf16x8*)(qrow + j * 32);
        }
        f32x4 o[8];
#pragma unroll
        for (int i = 0; i < 8; ++i) o[i] = (f32x4)(0.f);
        float m_ = -1e30f, l_ = 0.f;

        const int ntile = qblk + 1;
        for (int tile = 0; tile < ntile; ++tile) {
            const int t0 = tile * 64;
            {
                const char* kbase = (const char*)(qkv + (rb + t0) * LD + 4096);
#pragma unroll
                for (int i = 0; i < 4; ++i) {
                    const int c = i * 256 + t;
                    const int krow = c >> 4;
                    gload16(kbase + (size_t)krow * (LD * 2) + (((c & 15) * 16) ^ ((krow & 7) << 4)),
                            (char*)Kl + (i * 256 + wid * 64) * 16);
                }
            }
            {
                const unsigned short* vs = qkv + (rb + t0 + lane) * LD + 4224 + wid * 32;
                u16x8 v0 = *(const u16x8*)vs;
                u16x8 v1 = *(const u16x8*)(vs + 8);
                u16x8 v2 = *(const u16x8*)(vs + 16);
                u16x8 v3 = *(const u16x8*)(vs + 24);
                const int kb = 2 * lane;
#pragma unroll
                for (int e = 0; e < 8; ++e) {
                    int dd = wid * 32 + e;
                    *(unsigned short*)((char*)Vt + dd * 128 + (kb ^ ((dd & 7) << 4))) = v0[e];
                    dd += 8;
                    *(unsigned short*)((char*)Vt + dd * 128 + (kb ^ ((dd & 7) << 4))) = v1[e];
                    dd += 8;
                    *(unsigned short*)((char*)Vt + dd * 128 + (kb ^ ((dd & 7) << 4))) = v2[e];
                    dd += 8;
                    *(unsigned short*)((char*)Vt + dd * 128 + (kb ^ ((dd & 7) << 4))) = v3[e];
                }
            }
            __syncthreads();

            f32x4 s4[4];
#pragma unroll
            for (int ct = 0; ct < 4; ++ct) {
                s4[ct] = (f32x4)(0.f);
                const int row = ct * 16 + l15;
                const int swz = (row & 7) << 4;
#pragma unroll
                for (int j = 0; j < 4; ++j) {
                    bf16x8 kf = *(const bf16x8*)((const char*)Kl + row * 256 +
                                                 ((j * 64 + lg * 16) ^ swz));
                    s4[ct] = __builtin_amdgcn_mfma_f32_16x16x32_bf16(kf, qf[j], s4[ct], 0, 0, 0);
                }
            }

            const float base = slope2 * (float)(t0 + lg * 4) - aq;
            float p4[4][4];
            float mx = -1e30f;
            const bool lastt = (tile == ntile - 1);
            const int dbase = t0 + lg * 4 - qlane;
#pragma unroll
            for (int ct = 0; ct < 4; ++ct) {
                const float bbc = base + slope2 * 16.f * (float)ct;
#pragma unroll
                for (int r = 0; r < 4; ++r) {
                    float sc = fmaf(s4[ct][r], scale2,
                                    bbc + (r == 0 ? 0.f : (r == 1 ? sr1 : (r == 2 ? sr2 : sr3))));
                    if (lastt && (dbase + ct * 16 + r > 0)) sc = -1e30f;
                    p4[ct][r] = sc;
                    mx = fmaxf(mx, sc);
                }
            }
            mx = fmaxf(mx, __shfl_xor(mx, 16));
            mx = fmaxf(mx, __shfl_xor(mx, 32));

            if (!__all(mx <= m_ + 8.0f)) {
                const float mnew = fmaxf(m_, mx);
                const float corr = exp2f(m_ - mnew);
                m_ = mnew;
                l_ *= corr;
                float cr[4];
#pragma unroll
                for (int r = 0; r < 4; ++r) cr[r] = __shfl(corr, lg * 4 + r);
#pragma unroll
                for (int n = 0; n < 8; ++n) {
                    o[n][0] *= cr[0]; o[n][1] *= cr[1];
                    o[n][2] *= cr[2]; o[n][3] *= cr[3];
                }
            }

            float rs = 0.f;
#pragma unroll
            for (int ct = 0; ct < 4; ++ct)
#pragma unroll
                for (int r = 0; r < 4; ++r) {
                    const float pv = exp2f(p4[ct][r] - m_);
                    p4[ct][r] = pv;
                    rs += pv;
                }
            rs += __shfl_xor(rs, 16);
            rs += __shfl_xor(rs, 32);
            l_ += rs;

            {
                char* pb = (char*)&Pl[wid][0] + l15 * 128;
                const int swz = (l15 & 7) << 4;
#pragma unroll
                for (int ct = 0; ct < 4; ++ct) {
                    u16x4 w;
                    w[0] = f2bf_hw(p4[ct][0]); w[1] = f2bf_hw(p4[ct][1]);
                    w[2] = f2bf_hw(p4[ct][2]); w[3] = f2bf_hw(p4[ct][3]);
                    *(u16x4*)(pb + ((ct * 32 + lg * 8) ^ swz)) = w;
                }
            }

            const char* pb = (const char*)&Pl[wid][0] + l15 * 128;
            const int pswz = (l15 & 7) << 4;
            bf16x8 pa0 = *(const bf16x8*)(pb + ((lg * 16) ^ pswz));
            bf16x8 pa1 = *(const bf16x8*)(pb + ((64 + lg * 16) ^ pswz));
#pragma unroll
            for (int n = 0; n < 8; ++n) {
                const int dd = n * 16 + l15;
                const int vswz = (dd & 7) << 4;
                bf16x8 vf0 = *(const bf16x8*)((const char*)Vt + dd * 128 + ((lg * 16) ^ vswz));
                bf16x8 vf1 = *(const bf16x8*)((const char*)Vt + dd * 128 + ((64 + lg * 16) ^ vswz));
                f32x4 a4 = __builtin_amdgcn_mfma_f32_16x16x32_bf16(pa0, vf0, o[n], 0, 0, 0);
                o[n] = __builtin_amdgcn_mfma_f32_16x16x32_bf16(pa1, vf1, a4, 0, 0, 0);
            }
            __syncthreads();
        }

        const float rl = 1.f / l_;
        float rv[4];
#pragma unroll
        for (int r = 0; r < 4; ++r) rv[r] = __shfl(rl, lg * 4 + r);
#pragma unroll
        for (int n = 0; n < 8; ++n)
#pragma unroll
            for (int r = 0; r < 4; ++r) {
                const int q = q0w + lg * 4 + r;
                attn[(rb + q) * 4096 + h * 128 + n * 16 + l15] = f2bf(o[n][r] * rv[r]);
            }
    }
}

// ---------- launch ----------
extern "C" void kernel_launch(void* const* d_in, const int* in_sizes, int n_in,
                              void* d_out, int out_size, void* d_ws, size_t ws_size,
                              hipStream_t stream) {
    const float* hidden = (const float*)d_in[0];
    const float* Wqkv   = (const float*)d_in[1];
    const float* Wo     = (const float*)d_in[2];
    float* out = (float*)d_out;
    char* ws = (char*)d_ws;

    const int B = 2, S = 2048, H = 4096, NQ = 4352;
    const int M = B * S;

    unsigned short* hb  = (unsigned short*)(ws);                            // hidden bf16, later attn out
    unsigned short* wT  = (unsigned short*)(ws + 33554432);                 // WqkvT, later WoT
    unsigned short* qkv = (unsigned short*)(ws + 33554432 + 35651584);      // qkv bf16

    cast_bf16_kernel<<<(M * H / 8) / 256, 256, 0, stream>>>(hidden, hb, M * H / 8);
    transpose_cast_kernel<<<dim3(NQ / 32, H / 32), 256, 0, stream>>>(Wqkv, wT, H, NQ);
    gemm_kernel<1><<<dim3(NQ / 128, M / 128), 256, 0, stream>>>(hb, wT, qkv, M, NQ, H);
    transpose_cast_kernel<<<dim3(H / 32, H / 32), 256, 0, stream>>>(Wo, wT, H, H);
    attn_kernel<<<dim3(16, 32, 2), 256, 0, stream>>>(qkv, hb, S);
    gemm256_kernel<0><<<dim3(256), 512, 0, stream>>>(hb, wT, out, H, H);
}

// Round 8
// 520.935 us; speedup vs baseline: 1.0788x; 1.0651x over previous
//
#include <hip/hip_runtime.h>
#include <hip/hip_bf16.h>

// ---------- types ----------
typedef __attribute__((ext_vector_type(8))) short bf16x8;
typedef __attribute__((ext_vector_type(4))) float f32x4;
typedef __attribute__((ext_vector_type(8))) unsigned short u16x8;
typedef __attribute__((ext_vector_type(4))) unsigned short u16x4;

__device__ __forceinline__ unsigned short f2bf(float x) {
    union { float f; unsigned u; } v; v.f = x;
    unsigned r = v.u + 0x7fff + ((v.u >> 16) & 1);   // RNE
    return (unsigned short)(r >> 16);
}

__device__ __forceinline__ unsigned short f2bf_hw(float x) {
    __hip_bfloat16 h = __float2bfloat16(x);
    return *reinterpret_cast<unsigned short*>(&h);
}

__device__ __forceinline__ void gload16(const void* g, void* l) {
    __builtin_amdgcn_global_load_lds(
        (const __attribute__((address_space(1))) void*)g,
        (__attribute__((address_space(3))) void*)l, 16, 0, 0);
}

// ---------- cast fp32 -> bf16, 8 elems/thread ----------
__global__ __launch_bounds__(256) void cast_bf16_kernel(
    const float* __restrict__ src, unsigned short* __restrict__ dst, int n8) {
    int i = blockIdx.x * 256 + threadIdx.x;
    if (i >= n8) return;
    const float4* s = (const float4*)src + (size_t)i * 2;
    float4 a = s[0], b = s[1];
    u16x8 o;
    o[0] = f2bf(a.x); o[1] = f2bf(a.y); o[2] = f2bf(a.z); o[3] = f2bf(a.w);
    o[4] = f2bf(b.x); o[5] = f2bf(b.y); o[6] = f2bf(b.z); o[7] = f2bf(b.w);
    *(u16x8*)(dst + (size_t)i * 8) = o;
}

// ---------- transpose + cast: src fp32 [R][C] -> dst bf16 [C][R] ----------
__global__ __launch_bounds__(256) void transpose_cast_kernel(
    const float* __restrict__ src, unsigned short* __restrict__ dst, int R, int C) {
    __shared__ float tile[32][33];
    const int bx = blockIdx.x * 32, by = blockIdx.y * 32;
    const int tx = threadIdx.x & 31, ty = threadIdx.x >> 5;  // 32 x 8
#pragma unroll
    for (int i = 0; i < 32; i += 8)
        tile[ty + i][tx] = src[(size_t)(by + ty + i) * C + (bx + tx)];
    __syncthreads();
#pragma unroll
    for (int i = 0; i < 32; i += 8)
        dst[(size_t)(bx + ty + i) * R + (by + tx)] = f2bf(tile[tx][ty + i]);
}

// ---------- GEMM (m97 128x128 structure), used for GEMM1 (N=4352) ----------
template <int OUTBF>
__global__ __launch_bounds__(256) void gemm_kernel(
    const unsigned short* __restrict__ A, const unsigned short* __restrict__ BT,
    void* __restrict__ Cp, int M, int N, int K) {
    __shared__ unsigned short Al[2][128 * 32];
    __shared__ unsigned short Bl[2][128 * 32];
    const int t = threadIdx.x;
    const int wid = t >> 6, lane = t & 63;
    const int l15 = lane & 15, lg = lane >> 4;
    const int bm = blockIdx.y * 128, bn = blockIdx.x * 128;
    const int wm = (wid >> 1) * 64, wn = (wid & 1) * 64;

    f32x4 acc[4][4];
#pragma unroll
    for (int i = 0; i < 4; ++i)
#pragma unroll
        for (int j = 0; j < 4; ++j) acc[i][j] = (f32x4)(0.f);

    const int nk = K >> 5;
    const int c0 = t, c1 = t + 256;

    auto stage = [&](int buf, int kt) {
        const unsigned short* Ab = A + (size_t)bm * K + kt * 32;
        const unsigned short* Bb = BT + (size_t)bn * K + kt * 32;
        gload16(Ab + (size_t)(c0 >> 2) * K + (c0 & 3) * 8, &Al[buf][wid * 64 * 8]);
        gload16(Ab + (size_t)(c1 >> 2) * K + (c1 & 3) * 8, &Al[buf][(256 + wid * 64) * 8]);
        gload16(Bb + (size_t)(c0 >> 2) * K + (c0 & 3) * 8, &Bl[buf][wid * 64 * 8]);
        gload16(Bb + (size_t)(c1 >> 2) * K + (c1 & 3) * 8, &Bl[buf][(256 + wid * 64) * 8]);
    };

    stage(0, 0);
    __syncthreads();
    for (int kt = 0; kt < nk; ++kt) {
        const int cur = kt & 1;
        if (kt + 1 < nk) stage(cur ^ 1, kt + 1);
        bf16x8 af[4], bfr[4];
#pragma unroll
        for (int i = 0; i < 4; ++i) {
            af[i]  = *(const bf16x8*)&Al[cur][(wm + i * 16 + l15) * 32 + lg * 8];
            bfr[i] = *(const bf16x8*)&Bl[cur][(wn + i * 16 + l15) * 32 + lg * 8];
        }
#pragma unroll
        for (int i = 0; i < 4; ++i)
#pragma unroll
            for (int j = 0; j < 4; ++j)
                acc[i][j] = __builtin_amdgcn_mfma_f32_16x16x32_bf16(af[i], bfr[j], acc[i][j], 0, 0, 0);
        __syncthreads();
    }

#pragma unroll
    for (int i = 0; i < 4; ++i)
#pragma unroll
        for (int j = 0; j < 4; ++j)
#pragma unroll
            for (int r = 0; r < 4; ++r) {
                const int row = bm + wm + i * 16 + lg * 4 + r;
                const int col = bn + wn + j * 16 + l15;
                if (OUTBF) ((unsigned short*)Cp)[(size_t)row * N + col] = f2bf(acc[i][j][r]);
                else       ((float*)Cp)[(size_t)row * N + col] = acc[i][j][r];
            }
}

// ---------- GEMM2 v2: 256x256 8-phase, template-faithful quadrant schedule ----------
// 8 waves (2 A-halves x 4 N-quarters), BK=64, LDS 128KB = 2buf x {A0,A1,B0,B1}.
// Quadrant order per K-tile: (m0,n0),(m0,n1),(m1,n1),(m1,n0).
// Regs: acc 8x4 f32x4 (128) + afq[4][2] (32, reloaded ph1/ph3) + b0,b1 (16+16).
// Reads/phase: 12/4/8/0. Stage: exactly 1 half-tile (2 gloads) per phase:
//   ph1 Ab(1,0)<-kto  ph2 Ab(1,1)<-kto  ph3 Bb(0,0)<-kne  ph4 Bb(0,1)<-kne
//   ph5 Ab(0,0)<-kne  ph6 Ab(0,1)<-kne  ph7 Bb(1,0)<-kno  ph8 Bb(1,1)<-kno
// Gates vmcnt(4) at ph4/ph8: of 12 outstanding, oldest 8 = the 4 halves read
// next. Every stage lands >=1 phase after target death, >=3 phases pre-gate.
#define SYNC1() do { __builtin_amdgcn_s_barrier(); \
    asm volatile("s_waitcnt lgkmcnt(0)" ::: "memory"); } while (0)
#define GATE4() do { asm volatile("s_waitcnt vmcnt(4)" ::: "memory"); \
    __builtin_amdgcn_s_barrier(); __builtin_amdgcn_sched_barrier(0); } while (0)

template <int OUTBF>
__global__ __launch_bounds__(512, 2) void gemm256_kernel(
    const unsigned short* __restrict__ A, const unsigned short* __restrict__ BT,
    void* __restrict__ Cp, int K, int N) {
    __shared__ __align__(16) char lds[131072];
    const int t = threadIdx.x;
    const int wid = t >> 6, lane = t & 63;
    const int l15 = lane & 15, lg = lane >> 4;
    // rect XCD map: 16x16 tile grid, each XCD owns a 4x8 rectangle
    const int xcd = blockIdx.x & 7, idx = blockIdx.x >> 3;
    const int bm = ((xcd >> 1) * 4 + (idx >> 3)) * 256;
    const int bn = ((xcd & 1) * 8 + (idx & 7)) * 256;
    const int wmh = wid >> 2;            // wave A-half (rows wmh*128)
    const int wq  = wid & 3;             // wave N quarter (cols wq*64)
    const int bhf = wq >> 1;             // B half this wave reads
    const int br0 = (wq & 1) * 64;       // row base within B half

    auto Ab = [&](int b, int h) -> char* { return lds + ((b * 2 + h) << 14); };
    auto Bb = [&](int b, int h) -> char* { return lds + 65536 + ((b * 2 + h) << 14); };

    // stage one 16KB half: linear LDS dest, inverse-swizzled global source
    auto stage = [&](char* halfBase, const unsigned short* mat, int rowBase, int kt) {
#pragma unroll
        for (int j = 0; j < 2; ++j) {
            const int dbase = ((j << 3) + wid) << 10;
            const int q = (dbase + lane * 16) ^ (lane & 32);   // logical byte
            const int p = q >> 13, r = (q >> 6) & 127, cb = q & 63;
            gload16(mat + (size_t)(rowBase + r) * K + (kt << 6) + (p << 5) + (cb >> 1),
                    halfBase + dbase);
        }
    };

    f32x4 acc[8][4];
#pragma unroll
    for (int i = 0; i < 8; ++i)
#pragma unroll
        for (int j = 0; j < 4; ++j) acc[i][j] = (f32x4)(0.f);

    bf16x8 afq[4][2];          // current A quadrant (4 row-frags x 2 kk)
    bf16x8 b0[2][2], b1[2][2]; // B quadrants n0 / n1

    auto ldAq = [&](int b, int mh) {      // 8 ds_read_b128
        const char* base = Ab(b, wmh);
#pragma unroll
        for (int i = 0; i < 4; ++i) {
            const int r = mh * 64 + i * 16 + l15;
            const int sw = ((r >> 3) & 1) << 5;
#pragma unroll
            for (int kk = 0; kk < 2; ++kk)
                afq[i][kk] = *(const bf16x8*)(base + ((kk * 8192 + r * 64 + lg * 16) ^ sw));
        }
    };
    auto ldBq = [&](bf16x8 (&bq)[2][2], int b, int nh) {  // 4 ds_read_b128
        const char* base = Bb(b, bhf);
#pragma unroll
        for (int i = 0; i < 2; ++i) {
            const int r = br0 + (nh * 2 + i) * 16 + l15;
            const int sw = ((r >> 3) & 1) << 5;
#pragma unroll
            for (int kk = 0; kk < 2; ++kk)
                bq[i][kk] = *(const bf16x8*)(base + ((kk * 8192 + r * 64 + lg * 16) ^ sw));
        }
    };
    auto MFq = [&](int mh, int nh, bf16x8 (&bq)[2][2]) {  // 16 MFMA
        __builtin_amdgcn_s_setprio(1);
#pragma unroll
        for (int i = 0; i < 4; ++i)
#pragma unroll
            for (int j = 0; j < 2; ++j)
#pragma unroll
                for (int kk = 0; kk < 2; ++kk)
                    acc[mh * 4 + i][nh * 2 + j] = __builtin_amdgcn_mfma_f32_16x16x32_bf16(
                        afq[i][kk], bq[j][kk], acc[mh * 4 + i][nh * 2 + j], 0, 0, 0);
        __builtin_amdgcn_s_setprio(0);
    };

    // ---- prologue: buf0 all 4 halves <- kt0; buf1 B halves <- kt1 ----
    stage(Ab(0, 0), A, bm, 0);
    stage(Ab(0, 1), A, bm + 128, 0);
    stage(Bb(0, 0), BT, bn, 0);
    stage(Bb(0, 1), BT, bn + 128, 0);
    stage(Bb(1, 0), BT, bn, 1);
    stage(Bb(1, 1), BT, bn + 128, 1);
    asm volatile("s_waitcnt vmcnt(4)" ::: "memory");   // buf0 landed
    __builtin_amdgcn_s_barrier();
    __builtin_amdgcn_sched_barrier(0);

    const int kmask = (K >> 6) - 1;
    const int niter = K >> 7;
    for (int it = 0; it < niter; ++it) {
        const int kto = 2 * it + 1;
        const int kne = (2 * it + 2) & kmask;   // wraps harmlessly on last iters
        const int kno = (2 * it + 3) & kmask;
        // ph1: (m0,n0) of buf0
        ldAq(0, 0); ldBq(b0, 0, 0);
        stage(Ab(1, 0), A, bm, kto);
        SYNC1(); MFq(0, 0, b0); __builtin_amdgcn_s_barrier();
        // ph2: (m0,n1)
        ldBq(b1, 0, 1);
        stage(Ab(1, 1), A, bm + 128, kto);
        SYNC1(); MFq(0, 1, b1); __builtin_amdgcn_s_barrier();
        // ph3: (m1,n1)
        ldAq(0, 1);
        stage(Bb(0, 0), BT, bn, kne);
        SYNC1(); MFq(1, 1, b1); __builtin_amdgcn_s_barrier();
        // ph4: (m1,n0); gate buf1
        stage(Bb(0, 1), BT, bn + 128, kne);
        SYNC1(); MFq(1, 0, b0); GATE4();
        // ph5: (m0,n0) of buf1
        ldAq(1, 0); ldBq(b0, 1, 0);
        stage(Ab(0, 0), A, bm, kne);
        SYNC1(); MFq(0, 0, b0); __builtin_amdgcn_s_barrier();
        // ph6: (m0,n1)
        ldBq(b1, 1, 1);
        stage(Ab(0, 1), A, bm + 128, kne);
        SYNC1(); MFq(0, 1, b1); __builtin_amdgcn_s_barrier();
        // ph7: (m1,n1)
        ldAq(1, 1);
        stage(Bb(1, 0), BT, bn, kno);
        SYNC1(); MFq(1, 1, b1); __builtin_amdgcn_s_barrier();
        // ph8: (m1,n0); gate buf0
        stage(Bb(1, 1), BT, bn + 128, kno);
        SYNC1(); MFq(1, 0, b0); GATE4();
    }

#pragma unroll
    for (int mi = 0; mi < 8; ++mi)
#pragma unroll
        for (int ni = 0; ni < 4; ++ni)
#pragma unroll
            for (int rr = 0; rr < 4; ++rr) {
                const size_t off = (size_t)(bm + wmh * 128 + mi * 16 + lg * 4 + rr) * N +
                                   bn + wq * 64 + ni * 16 + l15;
                if (OUTBF) ((unsigned short*)Cp)[off] = f2bf(acc[mi][ni][rr]);
                else       ((float*)Cp)[off] = acc[mi][ni][rr];
            }
}

// ---------- flash attention v4 (MQA, ALiBi, causal, swapped-QK softmax) ----------
__global__ __launch_bounds__(256, 4) void attn_kernel(
    const unsigned short* __restrict__ qkv, unsigned short* __restrict__ attn, int S) {
    constexpr int LD = 4352;
    __shared__ unsigned short Kl[64 * 128];
    __shared__ unsigned short Vt[128 * 64];
    __shared__ unsigned short Pl[4][16 * 64];
    const int t = threadIdx.x, wid = t >> 6;
    const int lane = t & 63, l15 = lane & 15, lg = lane >> 4;
    const int h = blockIdx.y, b = blockIdx.z;
    const size_t rb = (size_t)b * S;
    const int nQB = S >> 6;                       // 32
    const float scale2 = 0.08838834764831845f * 1.4426950408889634f;
    const float slope2 = exp2f(-0.25f * (float)(h + 1)) * 1.4426950408889634f;
    const float sr1 = slope2, sr2 = slope2 * 2.f, sr3 = slope2 * 3.f;

    for (int half = 0; half < 2; ++half) {
        const int qblk = half ? (nQB - 1 - (int)blockIdx.x) : (int)blockIdx.x;
        const int q0w = qblk * 64 + wid * 16;
        const int qlane = q0w + l15;
        const float aq = slope2 * (float)qlane;

        bf16x8 qf[4];
        {
            const unsigned short* qrow = qkv + (rb + qlane) * LD + h * 128 + lg * 8;
#pragma unroll
            for (int j = 0; j < 4; ++j) qf[j] = *(const bf16x8*)(qrow + j * 32);
        }
        f32x4 o[8];
#pragma unroll
        for (int i = 0; i < 8; ++i) o[i] = (f32x4)(0.f);
        float m_ = -1e30f, l_ = 0.f;

        const int ntile = qblk + 1;
        for (int tile = 0; tile < ntile; ++tile) {
            const int t0 = tile * 64;
            {
                const char* kbase = (const char*)(qkv + (rb + t0) * LD + 4096);
#pragma unroll
                for (int i = 0; i < 4; ++i) {
                    const int c = i * 256 + t;
                    const int krow = c >> 4;
                    gload16(kbase + (size_t)krow * (LD * 2) + (((c & 15) * 16) ^ ((krow & 7) << 4)),
                            (char*)Kl + (i * 256 + wid * 64) * 16);
                }
            }
            {
                const unsigned short* vs = qkv + (rb + t0 + lane) * LD + 4224 + wid * 32;
                u16x8 v0 = *(const u16x8*)vs;
                u16x8 v1 = *(const u16x8*)(vs + 8);
                u16x8 v2 = *(const u16x8*)(vs + 16);
                u16x8 v3 = *(const u16x8*)(vs + 24);
                const int kb = 2 * lane;
#pragma unroll
                for (int e = 0; e < 8; ++e) {
                    int dd = wid * 32 + e;
                    *(unsigned short*)((char*)Vt + dd * 128 + (kb ^ ((dd & 7) << 4))) = v0[e];
                    dd += 8;
                    *(unsigned short*)((char*)Vt + dd * 128 + (kb ^ ((dd & 7) << 4))) = v1[e];
                    dd += 8;
                    *(unsigned short*)((char*)Vt + dd * 128 + (kb ^ ((dd & 7) << 4))) = v2[e];
                    dd += 8;
                    *(unsigned short*)((char*)Vt + dd * 128 + (kb ^ ((dd & 7) << 4))) = v3[e];
                }
            }
            __syncthreads();

            f32x4 s4[4];
#pragma unroll
            for (int ct = 0; ct < 4; ++ct) {
                s4[ct] = (f32x4)(0.f);
                const int row = ct * 16 + l15;
                const int swz = (row & 7) << 4;
#pragma unroll
                for (int j = 0; j < 4; ++j) {
                    bf16x8 kf = *(const bf16x8*)((const char*)Kl + row * 256 +
                                                 ((j * 64 + lg * 16) ^ swz));
                    s4[ct] = __builtin_amdgcn_mfma_f32_16x16x32_bf16(kf, qf[j], s4[ct], 0, 0, 0);
                }
            }

            const float base = slope2 * (float)(t0 + lg * 4) - aq;
            float p4[4][4];
            float mx = -1e30f;
            const bool lastt = (tile == ntile - 1);
            const int dbase = t0 + lg * 4 - qlane;
#pragma unroll
            for (int ct = 0; ct < 4; ++ct) {
                const float bbc = base + slope2 * 16.f * (float)ct;
#pragma unroll
                for (int r = 0; r < 4; ++r) {
                    float sc = fmaf(s4[ct][r], scale2,
                                    bbc + (r == 0 ? 0.f : (r == 1 ? sr1 : (r == 2 ? sr2 : sr3))));
                    if (lastt && (dbase + ct * 16 + r > 0)) sc = -1e30f;
                    p4[ct][r] = sc;
                    mx = fmaxf(mx, sc);
                }
            }
            mx = fmaxf(mx, __shfl_xor(mx, 16));
            mx = fmaxf(mx, __shfl_xor(mx, 32));

            if (!__all(mx <= m_ + 8.0f)) {
                const float mnew = fmaxf(m_, mx);
                const float corr = exp2f(m_ - mnew);
                m_ = mnew;
                l_ *= corr;
                float cr[4];
#pragma unroll
                for (int r = 0; r < 4; ++r) cr[r] = __shfl(corr, lg * 4 + r);
#pragma unroll
                for (int n = 0; n < 8; ++n) {
                    o[n][0] *= cr[0]; o[n][1] *= cr[1];
                    o[n][2] *= cr[2]; o[n][3] *= cr[3];
                }
            }

            float rs = 0.f;
#pragma unroll
            for (int ct = 0; ct < 4; ++ct)
#pragma unroll
                for (int r = 0; r < 4; ++r) {
                    const float pv = exp2f(p4[ct][r] - m_);
                    p4[ct][r] = pv;
                    rs += pv;
                }
            rs += __shfl_xor(rs, 16);
            rs += __shfl_xor(rs, 32);
            l_ += rs;

            {
                char* pb = (char*)&Pl[wid][0] + l15 * 128;
                const int swz = (l15 & 7) << 4;
#pragma unroll
                for (int ct = 0; ct < 4; ++ct) {
                    u16x4 w;
                    w[0] = f2bf_hw(p4[ct][0]); w[1] = f2bf_hw(p4[ct][1]);
                    w[2] = f2bf_hw(p4[ct][2]); w[3] = f2bf_hw(p4[ct][3]);
                    *(u16x4*)(pb + ((ct * 32 + lg * 8) ^ swz)) = w;
                }
            }

            const char* pb = (const char*)&Pl[wid][0] + l15 * 128;
            const int pswz = (l15 & 7) << 4;
            bf16x8 pa0 = *(const bf16x8*)(pb + ((lg * 16) ^ pswz));
            bf16x8 pa1 = *(const bf16x8*)(pb + ((64 + lg * 16) ^ pswz));
#pragma unroll
            for (int n = 0; n < 8; ++n) {
                const int dd = n * 16 + l15;
                const int vswz = (dd & 7) << 4;
                bf16x8 vf0 = *(const bf16x8*)((const char*)Vt + dd * 128 + ((lg * 16) ^ vswz));
                bf16x8 vf1 = *(const bf16x8*)((const char*)Vt + dd * 128 + ((64 + lg * 16) ^ vswz));
                f32x4 a4 = __builtin_amdgcn_mfma_f32_16x16x32_bf16(pa0, vf0, o[n], 0, 0, 0);
                o[n] = __builtin_amdgcn_mfma_f32_16x16x32_bf16(pa1, vf1, a4, 0, 0, 0);
            }
            __syncthreads();
        }

        const float rl = 1.f / l_;
        float rv[4];
#pragma unroll
        for (int r = 0; r < 4; ++r) rv[r] = __shfl(rl, lg * 4 + r);
#pragma unroll
        for (int n = 0; n < 8; ++n)
#pragma unroll
            for (int r = 0; r < 4; ++r) {
                const int q = q0w + lg * 4 + r;
                attn[(rb + q) * 4096 + h * 128 + n * 16 + l15] = f2bf(o[n][r] * rv[r]);
            }
    }
}

// ---------- launch ----------
extern "C" void kernel_launch(void* const* d_in, const int* in_sizes, int n_in,
                              void* d_out, int out_size, void* d_ws, size_t ws_size,
                              hipStream_t stream) {
    const float* hidden = (const float*)d_in[0];
    const float* Wqkv   = (const float*)d_in[1];
    const float* Wo     = (const float*)d_in[2];
    float* out = (float*)d_out;
    char* ws = (char*)d_ws;

    const int B = 2, S = 2048, H = 4096, NQ = 4352;
    const int M = B * S;

    unsigned short* hb  = (unsigned short*)(ws);                            // hidden bf16, later attn out
    unsigned short* wT  = (unsigned short*)(ws + 33554432);                 // WqkvT, later WoT
    unsigned short* qkv = (unsigned short*)(ws + 33554432 + 35651584);      // qkv bf16

    cast_bf16_kernel<<<(M * H / 8) / 256, 256, 0, stream>>>(hidden, hb, M * H / 8);
    transpose_cast_kernel<<<dim3(NQ / 32, H / 32), 256, 0, stream>>>(Wqkv, wT, H, NQ);
    gemm_kernel<1><<<dim3(NQ / 128, M / 128), 256, 0, stream>>>(hb, wT, qkv, M, NQ, H);
    transpose_cast_kernel<<<dim3(H / 32, H / 32), 256, 0, stream>>>(Wo, wT, H, H);
    attn_kernel<<<dim3(16, 32, 2), 256, 0, stream>>>(qkv, hb, S);
    gemm256_kernel<0><<<dim3(256), 512, 0, stream>>>(hb, wT, out, H, H);
}

// Round 9
// 520.634 us; speedup vs baseline: 1.0794x; 1.0006x over previous
//
#include <hip/hip_runtime.h>
#include <hip/hip_bf16.h>

// ---------- types ----------
typedef __attribute__((ext_vector_type(8))) short bf16x8;
typedef __attribute__((ext_vector_type(4))) float f32x4;
typedef __attribute__((ext_vector_type(8))) unsigned short u16x8;
typedef __attribute__((ext_vector_type(4))) unsigned short u16x4;

__device__ __forceinline__ unsigned short f2bf(float x) {
    union { float f; unsigned u; } v; v.f = x;
    unsigned r = v.u + 0x7fff + ((v.u >> 16) & 1);   // RNE
    return (unsigned short)(r >> 16);
}

__device__ __forceinline__ unsigned short f2bf_hw(float x) {
    __hip_bfloat16 h = __float2bfloat16(x);
    return *reinterpret_cast<unsigned short*>(&h);
}

__device__ __forceinline__ void gload16(const void* g, void* l) {
    __builtin_amdgcn_global_load_lds(
        (const __attribute__((address_space(1))) void*)g,
        (__attribute__((address_space(3))) void*)l, 16, 0, 0);
}

// ---------- cast fp32 -> bf16, 8 elems/thread ----------
__global__ __launch_bounds__(256) void cast_bf16_kernel(
    const float* __restrict__ src, unsigned short* __restrict__ dst, int n8) {
    int i = blockIdx.x * 256 + threadIdx.x;
    if (i >= n8) return;
    const float4* s = (const float4*)src + (size_t)i * 2;
    float4 a = s[0], b = s[1];
    u16x8 o;
    o[0] = f2bf(a.x); o[1] = f2bf(a.y); o[2] = f2bf(a.z); o[3] = f2bf(a.w);
    o[4] = f2bf(b.x); o[5] = f2bf(b.y); o[6] = f2bf(b.z); o[7] = f2bf(b.w);
    *(u16x8*)(dst + (size_t)i * 8) = o;
}

// ---------- transpose + cast: src fp32 [R][C] -> dst bf16 [C][R] ----------
__global__ __launch_bounds__(256) void transpose_cast_kernel(
    const float* __restrict__ src, unsigned short* __restrict__ dst, int R, int C) {
    __shared__ float tile[32][33];
    const int bx = blockIdx.x * 32, by = blockIdx.y * 32;
    const int tx = threadIdx.x & 31, ty = threadIdx.x >> 5;  // 32 x 8
#pragma unroll
    for (int i = 0; i < 32; i += 8)
        tile[ty + i][tx] = src[(size_t)(by + ty + i) * C + (bx + tx)];
    __syncthreads();
#pragma unroll
    for (int i = 0; i < 32; i += 8)
        dst[(size_t)(bx + ty + i) * R + (by + tx)] = f2bf(tile[tx][ty + i]);
}

// ---------- GEMM (m97 128x128 structure), used for GEMM1 (N=4352) ----------
template <int OUTBF>
__global__ __launch_bounds__(256) void gemm_kernel(
    const unsigned short* __restrict__ A, const unsigned short* __restrict__ BT,
    void* __restrict__ Cp, int M, int N, int K) {
    __shared__ unsigned short Al[2][128 * 32];
    __shared__ unsigned short Bl[2][128 * 32];
    const int t = threadIdx.x;
    const int wid = t >> 6, lane = t & 63;
    const int l15 = lane & 15, lg = lane >> 4;
    const int bm = blockIdx.y * 128, bn = blockIdx.x * 128;
    const int wm = (wid >> 1) * 64, wn = (wid & 1) * 64;

    f32x4 acc[4][4];
#pragma unroll
    for (int i = 0; i < 4; ++i)
#pragma unroll
        for (int j = 0; j < 4; ++j) acc[i][j] = (f32x4)(0.f);

    const int nk = K >> 5;
    const int c0 = t, c1 = t + 256;

    auto stage = [&](int buf, int kt) {
        const unsigned short* Ab = A + (size_t)bm * K + kt * 32;
        const unsigned short* Bb = BT + (size_t)bn * K + kt * 32;
        gload16(Ab + (size_t)(c0 >> 2) * K + (c0 & 3) * 8, &Al[buf][wid * 64 * 8]);
        gload16(Ab + (size_t)(c1 >> 2) * K + (c1 & 3) * 8, &Al[buf][(256 + wid * 64) * 8]);
        gload16(Bb + (size_t)(c0 >> 2) * K + (c0 & 3) * 8, &Bl[buf][wid * 64 * 8]);
        gload16(Bb + (size_t)(c1 >> 2) * K + (c1 & 3) * 8, &Bl[buf][(256 + wid * 64) * 8]);
    };

    stage(0, 0);
    __syncthreads();
    for (int kt = 0; kt < nk; ++kt) {
        const int cur = kt & 1;
        if (kt + 1 < nk) stage(cur ^ 1, kt + 1);
        bf16x8 af[4], bfr[4];
#pragma unroll
        for (int i = 0; i < 4; ++i) {
            af[i]  = *(const bf16x8*)&Al[cur][(wm + i * 16 + l15) * 32 + lg * 8];
            bfr[i] = *(const bf16x8*)&Bl[cur][(wn + i * 16 + l15) * 32 + lg * 8];
        }
#pragma unroll
        for (int i = 0; i < 4; ++i)
#pragma unroll
            for (int j = 0; j < 4; ++j)
                acc[i][j] = __builtin_amdgcn_mfma_f32_16x16x32_bf16(af[i], bfr[j], acc[i][j], 0, 0, 0);
        __syncthreads();
    }

#pragma unroll
    for (int i = 0; i < 4; ++i)
#pragma unroll
        for (int j = 0; j < 4; ++j)
#pragma unroll
            for (int r = 0; r < 4; ++r) {
                const int row = bm + wm + i * 16 + lg * 4 + r;
                const int col = bn + wn + j * 16 + l15;
                if (OUTBF) ((unsigned short*)Cp)[(size_t)row * N + col] = f2bf(acc[i][j][r]);
                else       ((float*)Cp)[(size_t)row * N + col] = acc[i][j][r];
            }
}

// ---------- GEMM2 v3: 256x256 8-phase, conflict-free (r&7)<<4 LDS swizzle ----------
// 8 waves (2 A-halves x 4 N-quarters), BK=64, LDS 128KB = 2buf x {A0,A1,B0,B1}
// 16KB halves, row-major [128 rows][64 cols bf16] (128B rows),
// byte ^= ((row&7)<<4): frag-read chunk = (kk*4+lg) ^ (r&7) -> each consecutive
// lane-octet covers all 8 bank-groups (verified pattern from attn K-reads).
// gload16: linear wave-uniform dest + inverse-swizzled global source (rule 21).
// Schedule identical to R8: quadrants (m0,n0),(m0,n1),(m1,n1),(m1,n0);
// stages 1 half/phase; gates vmcnt(4) at ph4/ph8.
#define SYNC1() do { __builtin_amdgcn_s_barrier(); \
    asm volatile("s_waitcnt lgkmcnt(0)" ::: "memory"); } while (0)
#define GATE4() do { asm volatile("s_waitcnt vmcnt(4)" ::: "memory"); \
    __builtin_amdgcn_s_barrier(); __builtin_amdgcn_sched_barrier(0); } while (0)

template <int OUTBF>
__global__ __launch_bounds__(512, 2) void gemm256_kernel(
    const unsigned short* __restrict__ A, const unsigned short* __restrict__ BT,
    void* __restrict__ Cp, int K, int N) {
    __shared__ __align__(16) char lds[131072];
    const int t = threadIdx.x;
    const int wid = t >> 6, lane = t & 63;
    const int l15 = lane & 15, lg = lane >> 4;
    // rect XCD map: 16x16 tile grid, each XCD owns a 4x8 rectangle
    const int xcd = blockIdx.x & 7, idx = blockIdx.x >> 3;
    const int bm = ((xcd >> 1) * 4 + (idx >> 3)) * 256;
    const int bn = ((xcd & 1) * 8 + (idx & 7)) * 256;
    const int wmh = wid >> 2;            // wave A-half (rows wmh*128)
    const int wq  = wid & 3;             // wave N quarter (cols wq*64)
    const int bhf = wq >> 1;             // B half this wave reads
    const int br0 = (wq & 1) * 64;       // row base within B half

    auto Ab = [&](int b, int h) -> char* { return lds + ((b * 2 + h) << 14); };
    auto Bb = [&](int b, int h) -> char* { return lds + 65536 + ((b * 2 + h) << 14); };

    // stage one 16KB half: linear LDS dest; source = element whose swizzled
    // position is this lane's dest byte (XOR bits 4-6, row-invariant).
    auto stage = [&](char* halfBase, const unsigned short* mat, int rowBase, int kt) {
#pragma unroll
        for (int j = 0; j < 2; ++j) {
            const int dbase = ((j << 3) + wid) << 10;       // wave-uniform
            const int d = dbase + lane * 16;                // this lane's dest
            const int r = d >> 7;                           // row 0..127
            const int c2 = (d ^ ((r & 7) << 4)) & 127;      // logical col bytes
            gload16(mat + (size_t)(rowBase + r) * K + (kt << 6) + (c2 >> 1),
                    halfBase + dbase);
        }
    };

    f32x4 acc[8][4];
#pragma unroll
    for (int i = 0; i < 8; ++i)
#pragma unroll
        for (int j = 0; j < 4; ++j) acc[i][j] = (f32x4)(0.f);

    bf16x8 afq[4][2];          // current A quadrant (4 row-frags x 2 kk)
    bf16x8 b0[2][2], b1[2][2]; // B quadrants n0 / n1

    auto ldAq = [&](int b, int mh) {      // 8 ds_read_b128, conflict-free
        const char* base = Ab(b, wmh);
#pragma unroll
        for (int i = 0; i < 4; ++i) {
            const int r = mh * 64 + i * 16 + l15;
            const int sw = (r & 7) << 4;
#pragma unroll
            for (int kk = 0; kk < 2; ++kk)
                afq[i][kk] = *(const bf16x8*)(base + r * 128 + ((kk * 64 + lg * 16) ^ sw));
        }
    };
    auto ldBq = [&](bf16x8 (&bq)[2][2], int b, int nh) {  // 4 ds_read_b128
        const char* base = Bb(b, bhf);
#pragma unroll
        for (int i = 0; i < 2; ++i) {
            const int r = br0 + (nh * 2 + i) * 16 + l15;
            const int sw = (r & 7) << 4;
#pragma unroll
            for (int kk = 0; kk < 2; ++kk)
                bq[i][kk] = *(const bf16x8*)(base + r * 128 + ((kk * 64 + lg * 16) ^ sw));
        }
    };
    auto MFq = [&](int mh, int nh, bf16x8 (&bq)[2][2]) {  // 16 MFMA
        __builtin_amdgcn_s_setprio(1);
#pragma unroll
        for (int i = 0; i < 4; ++i)
#pragma unroll
            for (int j = 0; j < 2; ++j)
#pragma unroll
                for (int kk = 0; kk < 2; ++kk)
                    acc[mh * 4 + i][nh * 2 + j] = __builtin_amdgcn_mfma_f32_16x16x32_bf16(
                        afq[i][kk], bq[j][kk], acc[mh * 4 + i][nh * 2 + j], 0, 0, 0);
        __builtin_amdgcn_s_setprio(0);
    };

    // ---- prologue: buf0 all 4 halves <- kt0; buf1 B halves <- kt1 ----
    stage(Ab(0, 0), A, bm, 0);
    stage(Ab(0, 1), A, bm + 128, 0);
    stage(Bb(0, 0), BT, bn, 0);
    stage(Bb(0, 1), BT, bn + 128, 0);
    stage(Bb(1, 0), BT, bn, 1);
    stage(Bb(1, 1), BT, bn + 128, 1);
    asm volatile("s_waitcnt vmcnt(4)" ::: "memory");   // buf0 landed
    __builtin_amdgcn_s_barrier();
    __builtin_amdgcn_sched_barrier(0);

    const int kmask = (K >> 6) - 1;
    const int niter = K >> 7;
    for (int it = 0; it < niter; ++it) {
        const int kto = 2 * it + 1;
        const int kne = (2 * it + 2) & kmask;   // wraps harmlessly on last iters
        const int kno = (2 * it + 3) & kmask;
        // ph1: (m0,n0) of buf0
        ldAq(0, 0); ldBq(b0, 0, 0);
        stage(Ab(1, 0), A, bm, kto);
        SYNC1(); MFq(0, 0, b0); __builtin_amdgcn_s_barrier();
        // ph2: (m0,n1)
        ldBq(b1, 0, 1);
        stage(Ab(1, 1), A, bm + 128, kto);
        SYNC1(); MFq(0, 1, b1); __builtin_amdgcn_s_barrier();
        // ph3: (m1,n1)
        ldAq(0, 1);
        stage(Bb(0, 0), BT, bn, kne);
        SYNC1(); MFq(1, 1, b1); __builtin_amdgcn_s_barrier();
        // ph4: (m1,n0); gate buf1
        stage(Bb(0, 1), BT, bn + 128, kne);
        SYNC1(); MFq(1, 0, b0); GATE4();
        // ph5: (m0,n0) of buf1
        ldAq(1, 0); ldBq(b0, 1, 0);
        stage(Ab(0, 0), A, bm, kne);
        SYNC1(); MFq(0, 0, b0); __builtin_amdgcn_s_barrier();
        // ph6: (m0,n1)
        ldBq(b1, 1, 1);
        stage(Ab(0, 1), A, bm + 128, kne);
        SYNC1(); MFq(0, 1, b1); __builtin_amdgcn_s_barrier();
        // ph7: (m1,n1)
        ldAq(1, 1);
        stage(Bb(1, 0), BT, bn, kno);
        SYNC1(); MFq(1, 1, b1); __builtin_amdgcn_s_barrier();
        // ph8: (m1,n0); gate buf0
        stage(Bb(1, 1), BT, bn + 128, kno);
        SYNC1(); MFq(1, 0, b0); GATE4();
    }

#pragma unroll
    for (int mi = 0; mi < 8; ++mi)
#pragma unroll
        for (int ni = 0; ni < 4; ++ni)
#pragma unroll
            for (int rr = 0; rr < 4; ++rr) {
                const size_t off = (size_t)(bm + wmh * 128 + mi * 16 + lg * 4 + rr) * N +
                                   bn + wq * 64 + ni * 16 + l15;
                if (OUTBF) ((unsigned short*)Cp)[off] = f2bf(acc[mi][ni][rr]);
                else       ((float*)Cp)[off] = acc[mi][ni][rr];
            }
}

// ---------- flash attention v4 (MQA, ALiBi, causal, swapped-QK softmax) ----------
__global__ __launch_bounds__(256, 4) void attn_kernel(
    const unsigned short* __restrict__ qkv, unsigned short* __restrict__ attn, int S) {
    constexpr int LD = 4352;
    __shared__ unsigned short Kl[64 * 128];
    __shared__ unsigned short Vt[128 * 64];
    __shared__ unsigned short Pl[4][16 * 64];
    const int t = threadIdx.x, wid = t >> 6;
    const int lane = t & 63, l15 = lane & 15, lg = lane >> 4;
    const int h = blockIdx.y, b = blockIdx.z;
    const size_t rb = (size_t)b * S;
    const int nQB = S >> 6;                       // 32
    const float scale2 = 0.08838834764831845f * 1.4426950408889634f;
    const float slope2 = exp2f(-0.25f * (float)(h + 1)) * 1.4426950408889634f;
    const float sr1 = slope2, sr2 = slope2 * 2.f, sr3 = slope2 * 3.f;

    for (int half = 0; half < 2; ++half) {
        const int qblk = half ? (nQB - 1 - (int)blockIdx.x) : (int)blockIdx.x;
        const int q0w = qblk * 64 + wid * 16;
        const int qlane = q0w + l15;
        const float aq = slope2 * (float)qlane;

        bf16x8 qf[4];
        {
            const unsigned short* qrow = qkv + (rb + qlane) * LD + h * 128 + lg * 8;
#pragma unroll
            for (int j = 0; j < 4; ++j) qf[j] = *(const bf16x8*)(qrow + j * 32);
        }
        f32x4 o[8];
#pragma unroll
        for (int i = 0; i < 8; ++i) o[i] = (f32x4)(0.f);
        float m_ = -1e30f, l_ = 0.f;

        const int ntile = qblk + 1;
        for (int tile = 0; tile < ntile; ++tile) {
            const int t0 = tile * 64;
            {
                const char* kbase = (const char*)(qkv + (rb + t0) * LD + 4096);
#pragma unroll
                for (int i = 0; i < 4; ++i) {
                    const int c = i * 256 + t;
                    const int krow = c >> 4;
                    gload16(kbase + (size_t)krow * (LD * 2) + (((c & 15) * 16) ^ ((krow & 7) << 4)),
                            (char*)Kl + (i * 256 + wid * 64) * 16);
                }
            }
            {
                const unsigned short* vs = qkv + (rb + t0 + lane) * LD + 4224 + wid * 32;
                u16x8 v0 = *(const u16x8*)vs;
                u16x8 v1 = *(const u16x8*)(vs + 8);
                u16x8 v2 = *(const u16x8*)(vs + 16);
                u16x8 v3 = *(const u16x8*)(vs + 24);
                const int kb = 2 * lane;
#pragma unroll
                for (int e = 0; e < 8; ++e) {
                    int dd = wid * 32 + e;
                    *(unsigned short*)((char*)Vt + dd * 128 + (kb ^ ((dd & 7) << 4))) = v0[e];
                    dd += 8;
                    *(unsigned short*)((char*)Vt + dd * 128 + (kb ^ ((dd & 7) << 4))) = v1[e];
                    dd += 8;
                    *(unsigned short*)((char*)Vt + dd * 128 + (kb ^ ((dd & 7) << 4))) = v2[e];
                    dd += 8;
                    *(unsigned short*)((char*)Vt + dd * 128 + (kb ^ ((dd & 7) << 4))) = v3[e];
                }
            }
            __syncthreads();

            f32x4 s4[4];
#pragma unroll
            for (int ct = 0; ct < 4; ++ct) {
                s4[ct] = (f32x4)(0.f);
                const int row = ct * 16 + l15;
                const int swz = (row & 7) << 4;
#pragma unroll
                for (int j = 0; j < 4; ++j) {
                    bf16x8 kf = *(const bf16x8*)((const char*)Kl + row * 256 +
                                                 ((j * 64 + lg * 16) ^ swz));
                    s4[ct] = __builtin_amdgcn_mfma_f32_16x16x32_bf16(kf, qf[j], s4[ct], 0, 0, 0);
                }
            }

            const float base = slope2 * (float)(t0 + lg * 4) - aq;
            float p4[4][4];
            float mx = -1e30f;
            const bool lastt = (tile == ntile - 1);
            const int dbase = t0 + lg * 4 - qlane;
#pragma unroll
            for (int ct = 0; ct < 4; ++ct) {
                const float bbc = base + slope2 * 16.f * (float)ct;
#pragma unroll
                for (int r = 0; r < 4; ++r) {
                    float sc = fmaf(s4[ct][r], scale2,
                                    bbc + (r == 0 ? 0.f : (r == 1 ? sr1 : (r == 2 ? sr2 : sr3))));
                    if (lastt && (dbase + ct * 16 + r > 0)) sc = -1e30f;
                    p4[ct][r] = sc;
                    mx = fmaxf(mx, sc);
                }
            }
            mx = fmaxf(mx, __shfl_xor(mx, 16));
            mx = fmaxf(mx, __shfl_xor(mx, 32));

            if (!__all(mx <= m_ + 8.0f)) {
                const float mnew = fmaxf(m_, mx);
                const float corr = exp2f(m_ - mnew);
                m_ = mnew;
                l_ *= corr;
                float cr[4];
#pragma unroll
                for (int r = 0; r < 4; ++r) cr[r] = __shfl(corr, lg * 4 + r);
#pragma unroll
                for (int n = 0; n < 8; ++n) {
                    o[n][0] *= cr[0]; o[n][1] *= cr[1];
                    o[n][2] *= cr[2]; o[n][3] *= cr[3];
                }
            }

            float rs = 0.f;
#pragma unroll
            for (int ct = 0; ct < 4; ++ct)
#pragma unroll
                for (int r = 0; r < 4; ++r) {
                    const float pv = exp2f(p4[ct][r] - m_);
                    p4[ct][r] = pv;
                    rs += pv;
                }
            rs += __shfl_xor(rs, 16);
            rs += __shfl_xor(rs, 32);
            l_ += rs;

            {
                char* pb = (char*)&Pl[wid][0] + l15 * 128;
                const int swz = (l15 & 7) << 4;
#pragma unroll
                for (int ct = 0; ct < 4; ++ct) {
                    u16x4 w;
                    w[0] = f2bf_hw(p4[ct][0]); w[1] = f2bf_hw(p4[ct][1]);
                    w[2] = f2bf_hw(p4[ct][2]); w[3] = f2bf_hw(p4[ct][3]);
                    *(u16x4*)(pb + ((ct * 32 + lg * 8) ^ swz)) = w;
                }
            }

            const char* pb = (const char*)&Pl[wid][0] + l15 * 128;
            const int pswz = (l15 & 7) << 4;
            bf16x8 pa0 = *(const bf16x8*)(pb + ((lg * 16) ^ pswz));
            bf16x8 pa1 = *(const bf16x8*)(pb + ((64 + lg * 16) ^ pswz));
#pragma unroll
            for (int n = 0; n < 8; ++n) {
                const int dd = n * 16 + l15;
                const int vswz = (dd & 7) << 4;
                bf16x8 vf0 = *(const bf16x8*)((const char*)Vt + dd * 128 + ((lg * 16) ^ vswz));
                bf16x8 vf1 = *(const bf16x8*)((const char*)Vt + dd * 128 + ((64 + lg * 16) ^ vswz));
                f32x4 a4 = __builtin_amdgcn_mfma_f32_16x16x32_bf16(pa0, vf0, o[n], 0, 0, 0);
                o[n] = __builtin_amdgcn_mfma_f32_16x16x32_bf16(pa1, vf1, a4, 0, 0, 0);
            }
            __syncthreads();
        }

        const float rl = 1.f / l_;
        float rv[4];
#pragma unroll
        for (int r = 0; r < 4; ++r) rv[r] = __shfl(rl, lg * 4 + r);
#pragma unroll
        for (int n = 0; n < 8; ++n)
#pragma unroll
            for (int r = 0; r < 4; ++r) {
                const int q = q0w + lg * 4 + r;
                attn[(rb + q) * 4096 + h * 128 + n * 16 + l15] = f2bf(o[n][r] * rv[r]);
            }
    }
}

// ---------- launch ----------
extern "C" void kernel_launch(void* const* d_in, const int* in_sizes, int n_in,
                              void* d_out, int out_size, void* d_ws, size_t ws_size,
                              hipStream_t stream) {
    const float* hidden = (const float*)d_in[0];
    const float* Wqkv   = (const float*)d_in[1];
    const float* Wo     = (const float*)d_in[2];
    float* out = (float*)d_out;
    char* ws = (char*)d_ws;

    const int B = 2, S = 2048, H = 4096, NQ = 4352;
    const int M = B * S;

    unsigned short* hb  = (unsigned short*)(ws);                            // hidden bf16, later attn out
    unsigned short* wT  = (unsigned short*)(ws + 33554432);                 // WqkvT, later WoT
    unsigned short* qkv = (unsigned short*)(ws + 33554432 + 35651584);      // qkv bf16

    cast_bf16_kernel<<<(M * H / 8) / 256, 256, 0, stream>>>(hidden, hb, M * H / 8);
    transpose_cast_kernel<<<dim3(NQ / 32, H / 32), 256, 0, stream>>>(Wqkv, wT, H, NQ);
    gemm_kernel<1><<<dim3(NQ / 128, M / 128), 256, 0, stream>>>(hb, wT, qkv, M, NQ, H);
    transpose_cast_kernel<<<dim3(H / 32, H / 32), 256, 0, stream>>>(Wo, wT, H, H);
    attn_kernel<<<dim3(16, 32, 2), 256, 0, stream>>>(qkv, hb, S);
    gemm256_kernel<0><<<dim3(256), 512, 0, stream>>>(hb, wT, out, H, H);
}